// Round 16
// baseline (85.841 us; speedup 1.0000x reference)
//
#include <hip/hip_runtime.h>

#define N_NODES 50000
#define N_EDGES 800000
#define D 128            // D_IN == D_OUT == 128
#define D4 32            // D / 4
#define D2 64            // D / 2

#define BIN_LOG 6
#define BIN_ROWS 64                                     // rows per bin
#define NBINS ((N_NODES + BIN_ROWS - 1) / BIN_ROWS)     // 782
#define CAP 1280          // per-bin record bound: mean 1024, std 32 (+8 sigma)

#define NKEYS 512         // (row&63)*8 + (col>>13): row-major, col-slice minor

#define EPB 4096                                        // edges per partition block
#define NCHUNK ((N_EDGES + EPB - 1) / EPB)              // 196 partition blocks
#define GEMM_BLOCKS ((N_NODES + 63) / 64)               // 782
#define E4 (N_EDGES / 4)                                // 200000 int4 records
#define STRIDE_ST (NBINS + 2)                           // per-chunk starts row (ushort)

typedef __attribute__((ext_vector_type(8))) short bf16x8;   // 8 bf16 in 4 VGPRs
typedef __attribute__((ext_vector_type(4))) float f32x4;

// ---- bf16 pack/unpack helpers (RTNE pack; unpack is shift/mask) ----------
__device__ __forceinline__ unsigned bf16_1(float a) {
    unsigned u = __float_as_uint(a);
    return (u + 0x7fffu + ((u >> 16) & 1u)) >> 16;
}
__device__ __forceinline__ unsigned pack_bf16(float a, float b) {
    return bf16_1(a) | (bf16_1(b) << 16);
}
__device__ __forceinline__ float ubf_lo(unsigned u) {
    return __uint_as_float(u << 16);
}
__device__ __forceinline__ float ubf_hi(unsigned u) {
    return __uint_as_float(u & 0xffff0000u);
}

// ---------------------------------------------------------------------------
// prep: build Wt[col][k]=bf16(W[k][col]) (8192 uints, k-pairs packed).
// Nothing needs zeroing anymore — the pipeline is fully overwrite-based.
// ---------------------------------------------------------------------------
__global__ __launch_bounds__(256) void prep_wt(const float* __restrict__ w,
                                               unsigned* __restrict__ wtu) {
    const int i = blockIdx.x * 256 + threadIdx.x;
    if (i < D * 64) {
        const int col = i >> 6;                    // 0..127
        const int k2  = i & 63;                    // k-pair 0..63
        wtu[i] = pack_bf16(w[(size_t)(2 * k2) * D + col],
                           w[(size_t)(2 * k2 + 1) * D + col]);
    }
}

// ---------------------------------------------------------------------------
// Partition: 196 blocks x 256. Fully atomic-free at global scope.
// Per block: 16 edges/thread loaded once as int4/float4 -> LDS histogram over
// 782 bins -> LDS scan -> LDS counting sort of all 4096 records -> ONE
// contiguous 32 KB streaming write (uint4) + 1.6 KB starts table (ushort).
// Write amplification = 1; no cross-block sector sharing; no reserve atomics.
// Record: {.x = col<<16 | bf16(val), .y = (row&63)*8 | (col>>13)}.
// ---------------------------------------------------------------------------
__global__ __launch_bounds__(256) void partition_edges(
        const int4* __restrict__ rowi4, const int4* __restrict__ coli4,
        const float4* __restrict__ vals4,
        uint2* __restrict__ blk_rec, ushort* __restrict__ blk_starts) {
    __shared__ int   hist[NBINS];
    __shared__ int   sts[NBINS + 1];
    __shared__ int   wsum[4], woff[4];
    __shared__ uint2 recs[EPB];                     // 32 KB
    const int tid = threadIdx.x;

    for (int i = tid; i < NBINS; i += 256) hist[i] = 0;
    __syncthreads();

    // 16 edges stashed in registers (single vector-load phase)
    union { int4 v4[4]; int a[16]; } R, C;
    union { float4 v4[4]; float a[16]; } V;
    const int base4 = blockIdx.x * (EPB / 4);
    #pragma unroll
    for (int q = 0; q < 4; ++q) {
        const int i4  = base4 + q * 256 + tid;
        const int i4c = (i4 < E4) ? i4 : (E4 - 1);
        R.v4[q] = rowi4[i4c];
        C.v4[q] = coli4[i4c];
        V.v4[q] = vals4[i4c];
        if (i4 >= E4) R.v4[q] = make_int4(-1, -1, -1, -1);
    }

    #pragma unroll
    for (int q = 0; q < 16; ++q)
        if (R.a[q] >= 0) atomicAdd(&hist[R.a[q] >> BIN_LOG], 1);
    __syncthreads();

    // exclusive scan over 782 bins: 4 keys/thread + wave scan + 4-wave combine
    int h[4];
    const int t4 = tid * 4;
    #pragma unroll
    for (int k = 0; k < 4; ++k) {
        const int idx = t4 + k;
        h[k] = (idx < NBINS) ? hist[idx] : 0;
    }
    const int s = h[0] + h[1] + h[2] + h[3];
    int v = s;
    #pragma unroll
    for (int off = 1; off < 64; off <<= 1) {
        const int t = __shfl_up(v, off);
        if ((tid & 63) >= off) v += t;
    }
    if ((tid & 63) == 63) wsum[tid >> 6] = v;
    __syncthreads();
    if (tid == 0) {
        int run = 0;
        #pragma unroll
        for (int w2 = 0; w2 < 4; ++w2) { woff[w2] = run; run += wsum[w2]; }
    }
    __syncthreads();
    int run = woff[tid >> 6] + (v - s);
    #pragma unroll
    for (int k = 0; k < 4; ++k) {
        const int idx = t4 + k;
        if (idx < NBINS) { sts[idx] = run; run += h[k]; }
    }
    if (t4 <= NBINS && NBINS < t4 + 4) sts[NBINS] = run;   // tid 195: block total
    __syncthreads();

    for (int i = tid; i < NBINS; i += 256) hist[i] = sts[i];   // rank cursor
    __syncthreads();

    #pragma unroll
    for (int q = 0; q < 16; ++q) {
        const int r = R.a[q];
        if (r >= 0) {
            const int b = r >> BIN_LOG;
            const int k = atomicAdd(&hist[b], 1);
            const unsigned c = (unsigned)C.a[q];
            recs[k] = make_uint2((c << 16) | bf16_1(V.a[q]),
                                 ((unsigned)(r & (BIN_ROWS - 1)) << 3) | (c >> 13));
        }
    }
    __syncthreads();

    // streaming write-out: 32 KB contiguous + starts table
    uint4* dst = (uint4*)(blk_rec + (size_t)blockIdx.x * EPB);
    const uint4* src = (const uint4*)recs;
    for (int i = tid; i < EPB / 2; i += 256) dst[i] = src[i];
    ushort* st = blk_starts + (size_t)blockIdx.x * STRIDE_ST;
    for (int i = tid; i <= NBINS; i += 256) st[i] = (ushort)sts[i];
}

// ---------------------------------------------------------------------------
// GEMM h = x @ W via bf16 MFMA (16x16x32). 782 blocks x 256; wave = 16 rows.
// Unchanged from R14 (known-good); now a SEPARATE dispatch for attribution.
// ---------------------------------------------------------------------------
__global__ __launch_bounds__(256) void gemm_mfma(const float4* __restrict__ x4,
                                                 const uint4* __restrict__ wt4,
                                                 ushort* __restrict__ hb) {
    const int lane = threadIdx.x & 63;
    const int r0   = blockIdx.x * 64 + (threadIdx.x >> 6) * 16;
    const int arow = r0 + (lane & 15);
    const int kg   = lane >> 4;                    // k-group 0..3
    const bool rok = (arow < N_NODES);

    bf16x8 afr[4];
    #pragma unroll
    for (int kc = 0; kc < 4; ++kc) {
        float4 f0 = make_float4(0.f, 0.f, 0.f, 0.f);
        float4 f1 = f0;
        if (rok) {
            const int c4 = kc * 8 + kg * 2;
            f0 = x4[(size_t)arow * D4 + c4];
            f1 = x4[(size_t)arow * D4 + c4 + 1];
        }
        union { bf16x8 v; unsigned u[4]; } a;
        a.u[0] = pack_bf16(f0.x, f0.y);
        a.u[1] = pack_bf16(f0.z, f0.w);
        a.u[2] = pack_bf16(f1.x, f1.y);
        a.u[3] = pack_bf16(f1.z, f1.w);
        afr[kc] = a.v;
    }

    f32x4 acc[8];
    #pragma unroll
    for (int t = 0; t < 8; ++t) acc[t] = (f32x4){0.f, 0.f, 0.f, 0.f};

    #pragma unroll
    for (int t = 0; t < 8; ++t) {
        const int col = t * 16 + (lane & 15);
        #pragma unroll
        for (int kc = 0; kc < 4; ++kc) {
            union { bf16x8 v; uint4 u; } b;
            b.u = wt4[(size_t)col * 16 + kc * 4 + kg];   // Wt row: 16 uint4
            acc[t] = __builtin_amdgcn_mfma_f32_16x16x32_bf16(afr[kc], b.v,
                                                             acc[t], 0, 0, 0);
        }
    }

    // C/D layout (verified m89): col = lane&15, row = (lane>>4)*4 + reg.
    #pragma unroll
    for (int t = 0; t < 8; ++t) {
        const int col = t * 16 + (lane & 15);
        #pragma unroll
        for (int j = 0; j < 4; ++j) {
            const int r = r0 + (lane >> 4) * 4 + j;
            if (r < N_NODES)
                hb[(size_t)r * D + col] = (ushort)bf16_1(acc[t][j]);
        }
    }
}

// ---------------------------------------------------------------------------
// Phase B: one block per bin (782 x 512).
// Front-end: read 196 per-chunk (start,count) entries (L2-resident table),
// LDS scan -> each thread binary-searches its <=3 record indices and loads the
// records into REGISTERS (no LDS staging). Then: 512-key LDS histogram/scan/
// scatter (records col-ordered within each row) + paired-row gather with
// fused bias + ReLU. No global atomics anywhere.
// ---------------------------------------------------------------------------
__global__ __launch_bounds__(512) void sort_gather(const ushort* __restrict__ blk_starts,
                                                   const uint2* __restrict__ blk_rec,
                                                   const uint2* __restrict__ hb2,
                                                   const float4* __restrict__ bias4,
                                                   float4* __restrict__ out4) {
    __shared__ int      chunk_s[NCHUNK];
    __shared__ int      chunkoff[NCHUNK + 1];
    __shared__ int      hcnt[NKEYS];
    __shared__ int      cur[NKEYS];
    __shared__ int      starts[NKEYS + 1];
    __shared__ int      wsum[8], woff[8];
    __shared__ unsigned sorted[CAP];

    const int bin = blockIdx.x;
    const int tid = threadIdx.x;

    // ---- per-chunk counts + scan (threads 0..255 participate) ----
    int cnt_c = 0;
    if (tid < NCHUNK) {
        const ushort* st = blk_starts + (size_t)tid * STRIDE_ST;
        const int s0 = st[bin];
        cnt_c = st[bin + 1] - s0;
        chunk_s[tid] = s0;
    }
    if (tid < NKEYS) { hcnt[tid] = 0; cur[tid] = 0; }
    if (tid < 256) {
        int v = cnt_c;
        #pragma unroll
        for (int off = 1; off < 64; off <<= 1) {
            const int t = __shfl_up(v, off);
            if ((tid & 63) >= off) v += t;
        }
        if ((tid & 63) == 63) wsum[tid >> 6] = v;
        __syncthreads();
        if (tid == 0) {
            int run = 0;
            #pragma unroll
            for (int w2 = 0; w2 < 4; ++w2) { woff[w2] = run; run += wsum[w2]; }
        }
        __syncthreads();
        if (tid <= NCHUNK) chunkoff[tid] = woff[tid >> 6] + v - cnt_c;
    } else {
        __syncthreads();
        __syncthreads();
    }
    __syncthreads();
    const int n = chunkoff[NCHUNK];

    // ---- load records into registers (<=3 per thread) ----
    uint2 rec[3];
    int nrec = 0;
    for (int i = tid; i < n; i += 512) {
        int lo = 0, hi = NCHUNK;                     // chunkoff[lo] <= i
        while (hi - lo > 1) {
            const int mid = (lo + hi) >> 1;
            if (chunkoff[mid] <= i) lo = mid; else hi = mid;
        }
        const int slot = i - chunkoff[lo];
        rec[nrec++] = blk_rec[(size_t)lo * EPB + chunk_s[lo] + slot];
    }

    // ---- 512-key histogram ----
    for (int k = 0; k < nrec; ++k) atomicAdd(&hcnt[rec[k].y & (NKEYS - 1)], 1);
    __syncthreads();

    // two-level inclusive scan over 512 keys
    {
        int v = hcnt[tid];
        #pragma unroll
        for (int off = 1; off < 64; off <<= 1) {
            const int t = __shfl_up(v, off);
            if ((tid & 63) >= off) v += t;
        }
        starts[tid + 1] = v;
        if ((tid & 63) == 63) wsum[tid >> 6] = v;
    }
    __syncthreads();
    if (tid == 0) {
        int run = 0;
        #pragma unroll
        for (int w2 = 0; w2 < 8; ++w2) { woff[w2] = run; run += wsum[w2]; }
        starts[0] = 0;
    }
    __syncthreads();
    starts[tid + 1] += woff[tid >> 6];
    __syncthreads();

    // ---- scatter into sorted[] ----
    for (int k = 0; k < nrec; ++k) {
        const int key = rec[k].y & (NKEYS - 1);
        const int p = atomicAdd(&cur[key], 1);
        sorted[starts[key] + p] = rec[k].x;
    }
    __syncthreads();

    // ---- gather: two rows per wave, lane owns 4 features ----
    const int wave = tid >> 6;
    const int lane = tid & 63;
    const int half = lane >> 5;                     // 0: row A, 1: row B
    const int hl   = lane & 31;                     // feature group 0..31
    const float4 b = bias4[hl];

    #pragma unroll
    for (int rp = 0; rp < 4; ++rp) {
        const int row  = wave + 16 * rp + 8 * half;
        const int node = bin * BIN_ROWS + row;
        int s = 0, len = 0;
        if (node < N_NODES) {
            s   = starts[row << 3];                 // row segment spans 8 keys
            len = starts[(row << 3) + 8] - s;
        }
        int lm = len;
        lm = max(lm, __shfl_xor(lm, 32));           // pair-max iteration count

        float4 acc = {0.f, 0.f, 0.f, 0.f};
        for (int j0 = 0; j0 < lm; j0 += 8) {
            uint2 hv[8];
            float vv[8];
            #pragma unroll
            for (int q = 0; q < 8; ++q) {
                const int jq = j0 + q;
                const int jj = (jq < len) ? (s + jq) : 0;
                unsigned ed = sorted[jj];            // LDS broadcast per half
                ed = (jq < len) ? ed : 0u;
                vv[q] = __uint_as_float((ed & 0xffffu) << 16);
                hv[q] = hb2[(size_t)(ed >> 16) * 32 + hl];   // 8B/lane, coalesced
            }
            #pragma unroll
            for (int q = 0; q < 8; ++q) {
                acc.x = fmaf(vv[q], ubf_lo(hv[q].x), acc.x);
                acc.y = fmaf(vv[q], ubf_hi(hv[q].x), acc.y);
                acc.z = fmaf(vv[q], ubf_lo(hv[q].y), acc.z);
                acc.w = fmaf(vv[q], ubf_hi(hv[q].y), acc.w);
            }
        }
        if (node < N_NODES) {
            float4 o;
            o.x = fmaxf(acc.x + b.x, 0.f);
            o.y = fmaxf(acc.y + b.y, 0.f);
            o.z = fmaxf(acc.z + b.z, 0.f);
            o.w = fmaxf(acc.w + b.w, 0.f);
            out4[(size_t)node * 32 + hl] = o;
        }
    }
}

extern "C" void kernel_launch(void* const* d_in, const int* in_sizes, int n_in,
                              void* d_out, int out_size, void* d_ws, size_t ws_size,
                              hipStream_t stream) {
    const float* x      = (const float*)d_in[0];   // [N_NODES, D]
    const float* weight = (const float*)d_in[1];   // [D, D]
    const float* bias   = (const float*)d_in[2];   // [D]
    const float* vals   = (const float*)d_in[3];   // [N_EDGES]
    const int*   rowi   = (const int*)d_in[4];     // [N_EDGES]
    const int*   coli   = (const int*)d_in[5];     // [N_EDGES]
    float* out = (float*)d_out;                    // [N_NODES, D]

    // Workspace layout (16B-aligned):
    //   hb         : N_NODES*128 ushorts (bf16 h)           = 12.8 MB
    //   wt         : 128*64 uints (bf16 W^T, k-packed)      = 32 KB
    //   blk_rec    : NCHUNK*EPB uint2 (bin-sorted records)  = 6.4 MB
    //   blk_starts : NCHUNK*(NBINS+2) ushorts               = 307 KB
    char* w = (char*)d_ws;
    ushort*   hb         = (ushort*)w;   w += (size_t)N_NODES * D * sizeof(ushort);
    unsigned* wt         = (unsigned*)w; w += (size_t)D * 64 * sizeof(unsigned);
    uint2*    blk_rec    = (uint2*)w;    w += (size_t)NCHUNK * EPB * sizeof(uint2);
    ushort*   blk_starts = (ushort*)w;

    // 1) build bf16 W^T (nothing needs zeroing — pipeline is overwrite-based)
    prep_wt<<<32, 256, 0, stream>>>(weight, wt);

    // 2) atomic-free partition: LDS counting sort + streaming block write-out
    partition_edges<<<NCHUNK, 256, 0, stream>>>((const int4*)rowi, (const int4*)coli,
                                                (const float4*)vals,
                                                blk_rec, blk_starts);

    // 3) GEMM (MFMA bf16) — separate dispatch for attribution
    gemm_mfma<<<GEMM_BLOCKS, 256, 0, stream>>>((const float4*)x, (const uint4*)wt, hb);

    // 4) per-bin 512-key sort + col-ordered gather + fused bias/ReLU
    sort_gather<<<NBINS, 512, 0, stream>>>(blk_starts, blk_rec, (const uint2*)hb,
                                           (const float4*)bias, (float4*)out);
}

// Round 17
// 78.641 us; speedup vs baseline: 1.0916x; 1.0916x over previous
//
#include <hip/hip_runtime.h>

#define N_NODES 50000
#define N_EDGES 800000
#define D 128            // D_IN == D_OUT == 128
#define D4 32            // D / 4

#define BIN_LOG 6
#define BIN_ROWS 64                                     // rows per bin
#define NBINS ((N_NODES + BIN_ROWS - 1) / BIN_ROWS)     // 782
#define CAP 1280          // per-bin total bound: mean 1024, std 32 (+8 sigma)

#define NKEYS 512         // (row&63)*8 + (col>>13): row-major, col-slice minor

#define EPB 4096                                        // edges per partition block
#define NCHUNK ((N_EDGES + EPB - 1) / EPB)              // 196 partition blocks
#define GEMM_BLOCKS ((N_NODES + 63) / 64)               // 782
#define E4 (N_EDGES / 4)                                // 200000 int4 records

#define CAP_CELL 24                                     // slots per (bin,chunk) cell
#define CELLS_PER_BIN (NCHUNK * CAP_CELL)               // 4704
#define CNTROW 784                                      // padded count row (ushort)

typedef __attribute__((ext_vector_type(8))) short bf16x8;   // 8 bf16 in 4 VGPRs
typedef __attribute__((ext_vector_type(4))) float f32x4;

// ---- bf16 pack/unpack helpers (RTNE pack; unpack is shift/mask) ----------
__device__ __forceinline__ unsigned bf16_1(float a) {
    unsigned u = __float_as_uint(a);
    return (u + 0x7fffu + ((u >> 16) & 1u)) >> 16;
}
__device__ __forceinline__ unsigned pack_bf16(float a, float b) {
    return bf16_1(a) | (bf16_1(b) << 16);
}
__device__ __forceinline__ float ubf_lo(unsigned u) {
    return __uint_as_float(u << 16);
}
__device__ __forceinline__ float ubf_hi(unsigned u) {
    return __uint_as_float(u & 0xffff0000u);
}

// ---------------------------------------------------------------------------
// prep: build Wt[col][k]=bf16(W[k][col]) (8192 uints, k-pairs packed).
// Nothing else needs zeroing — the whole pipeline is overwrite-based
// (cells' garbage slots are guarded by fresh cnt_t every call).
// ---------------------------------------------------------------------------
__global__ __launch_bounds__(256) void prep_wt(const float* __restrict__ w,
                                               unsigned* __restrict__ wtu) {
    const int i = blockIdx.x * 256 + threadIdx.x;
    if (i < D * 64) {
        const int col = i >> 6;                    // 0..127
        const int k2  = i & 63;                    // k-pair 0..63
        wtu[i] = pack_bf16(w[(size_t)(2 * k2) * D + col],
                           w[(size_t)(2 * k2 + 1) * D + col]);
    }
}

// ---------------------------------------------------------------------------
// Fused dispatch (256 threads).
//  Blocks [0, NCHUNK): partition. Per edge: ONE LDS cursor atomic + ONE direct
//    8B write into the block-exclusive cell cells[bin][chunk][slot] (192B cell
//    = exactly 3 sectors -> zero cross-block sector sharing), then a streaming
//    1.6KB transposed count row cnt_t[chunk][bin]. No scan, no global atomics.
//    Record: {.x = col<<16 | bf16(val), .y = (row&63)*8 | (col>>13)}.
//  Blocks [NCHUNK, +GEMM_BLOCKS): MFMA GEMM h = x@W (bf16 out), wave = 16 rows.
// ---------------------------------------------------------------------------
__global__ __launch_bounds__(256) void fused_partition_gemm(
        const float4* __restrict__ x4, const uint4* __restrict__ wt4,
        ushort* __restrict__ hb,
        const int4* __restrict__ rowi4, const int4* __restrict__ coli4,
        const float4* __restrict__ vals4,
        uint2* __restrict__ cells, ushort* __restrict__ cnt_t) {

    if (blockIdx.x < NCHUNK) {
        __shared__ int cur[NBINS];
        const int tid = threadIdx.x;
        for (int i = tid; i < NBINS; i += 256) cur[i] = 0;
        __syncthreads();

        // 16 edges stashed in registers (single vector-load phase)
        union { int4 v4[4]; int a[16]; } R, C;
        union { float4 v4[4]; float a[16]; } V;
        const int base4 = blockIdx.x * (EPB / 4);
        #pragma unroll
        for (int q = 0; q < 4; ++q) {
            const int i4  = base4 + q * 256 + tid;
            const int i4c = (i4 < E4) ? i4 : (E4 - 1);
            R.v4[q] = rowi4[i4c];
            C.v4[q] = coli4[i4c];
            V.v4[q] = vals4[i4c];
            if (i4 >= E4) R.v4[q] = make_int4(-1, -1, -1, -1);
        }

        #pragma unroll
        for (int q = 0; q < 16; ++q) {
            const int r = R.a[q];
            if (r >= 0) {
                const int b = r >> BIN_LOG;
                const int k = atomicAdd(&cur[b], 1);
                const unsigned c = (unsigned)C.a[q];
                if (k < CAP_CELL)
                    cells[((size_t)b * NCHUNK + blockIdx.x) * CAP_CELL + k] =
                        make_uint2((c << 16) | bf16_1(V.a[q]),
                                   ((unsigned)(r & (BIN_ROWS - 1)) << 3) | (c >> 13));
            }
        }
        __syncthreads();

        ushort* ct = cnt_t + (size_t)blockIdx.x * CNTROW;
        for (int i = tid; i < NBINS; i += 256)
            ct[i] = (ushort)min(cur[i], CAP_CELL);
        return;
    }

    // ---------------- MFMA GEMM: one wave = 16 output rows ----------------
    const int bid  = blockIdx.x - NCHUNK;
    const int lane = threadIdx.x & 63;
    const int r0   = bid * 64 + (threadIdx.x >> 6) * 16;
    const int arow = r0 + (lane & 15);
    const int kg   = lane >> 4;                    // k-group 0..3
    const bool rok = (arow < N_NODES);

    bf16x8 afr[4];
    #pragma unroll
    for (int kc = 0; kc < 4; ++kc) {
        float4 f0 = make_float4(0.f, 0.f, 0.f, 0.f);
        float4 f1 = f0;
        if (rok) {
            const int c4 = kc * 8 + kg * 2;
            f0 = x4[(size_t)arow * D4 + c4];
            f1 = x4[(size_t)arow * D4 + c4 + 1];
        }
        union { bf16x8 v; unsigned u[4]; } a;
        a.u[0] = pack_bf16(f0.x, f0.y);
        a.u[1] = pack_bf16(f0.z, f0.w);
        a.u[2] = pack_bf16(f1.x, f1.y);
        a.u[3] = pack_bf16(f1.z, f1.w);
        afr[kc] = a.v;
    }

    f32x4 acc[8];
    #pragma unroll
    for (int t = 0; t < 8; ++t) acc[t] = (f32x4){0.f, 0.f, 0.f, 0.f};

    #pragma unroll
    for (int t = 0; t < 8; ++t) {
        const int col = t * 16 + (lane & 15);
        #pragma unroll
        for (int kc = 0; kc < 4; ++kc) {
            union { bf16x8 v; uint4 u; } b;
            b.u = wt4[(size_t)col * 16 + kc * 4 + kg];   // Wt row: 16 uint4
            acc[t] = __builtin_amdgcn_mfma_f32_16x16x32_bf16(afr[kc], b.v,
                                                             acc[t], 0, 0, 0);
        }
    }

    // C/D layout (verified m89): col = lane&15, row = (lane>>4)*4 + reg.
    #pragma unroll
    for (int t = 0; t < 8; ++t) {
        const int col = t * 16 + (lane & 15);
        #pragma unroll
        for (int j = 0; j < 4; ++j) {
            const int r = r0 + (lane >> 4) * 4 + j;
            if (r < N_NODES)
                hb[(size_t)r * D + col] = (ushort)bf16_1(acc[t][j]);
        }
    }
}

// ---------------------------------------------------------------------------
// Phase B: one block per bin (782 x 512).
// Front-end: stage the bin's WHOLE cell stripe (37.6 KB, contiguous, uint4)
// into LDS + 196 L2-resident count reads. Then 512-key LDS histogram/scan/
// scatter (row-major, col-slice-minor keys -> row segments contiguous and
// col-ordered) + paired-row gather with fused bias + ReLU. No binary search,
// no divergent barriers, no global atomics.
// ---------------------------------------------------------------------------
__global__ __launch_bounds__(512) void sort_gather(const ushort* __restrict__ cnt_t,
                                                   const uint2* __restrict__ cells,
                                                   const uint2* __restrict__ hb2,
                                                   const float4* __restrict__ bias4,
                                                   float4* __restrict__ out4) {
    __shared__ ushort   cnt_c[NCHUNK];
    __shared__ uint2    raw[CELLS_PER_BIN];          // 37632 B
    __shared__ int      hcnt[NKEYS];
    __shared__ int      cur[NKEYS];
    __shared__ int      starts[NKEYS + 1];
    __shared__ int      wsum[8], woff[8];
    __shared__ unsigned sorted[CAP];

    const int bin = blockIdx.x;
    const int tid = threadIdx.x;

    if (tid < NCHUNK) cnt_c[tid] = cnt_t[(size_t)tid * CNTROW + bin];
    if (tid < NKEYS) { hcnt[tid] = 0; cur[tid] = 0; }

    // stage the bin's cell stripe: contiguous 37.6 KB, uint4-vectorized
    {
        const uint4* src = (const uint4*)(cells + (size_t)bin * CELLS_PER_BIN);
        uint4* dst = (uint4*)raw;
        for (int i = tid; i < CELLS_PER_BIN / 2; i += 512) dst[i] = src[i];
    }
    __syncthreads();

    // ---- 512-key histogram over valid slots ----
    for (int i = tid; i < CELLS_PER_BIN; i += 512) {
        const int c = i / CAP_CELL;
        const int s = i - c * CAP_CELL;
        if (s < (int)cnt_c[c]) atomicAdd(&hcnt[raw[i].y & (NKEYS - 1)], 1);
    }
    __syncthreads();

    // ---- two-level inclusive scan over 512 keys ----
    {
        int v = hcnt[tid];
        #pragma unroll
        for (int off = 1; off < 64; off <<= 1) {
            const int t = __shfl_up(v, off);
            if ((tid & 63) >= off) v += t;
        }
        starts[tid + 1] = v;
        if ((tid & 63) == 63) wsum[tid >> 6] = v;
    }
    __syncthreads();
    if (tid == 0) {
        int run = 0;
        #pragma unroll
        for (int w2 = 0; w2 < 8; ++w2) { woff[w2] = run; run += wsum[w2]; }
        starts[0] = 0;
    }
    __syncthreads();
    starts[tid + 1] += woff[tid >> 6];
    __syncthreads();

    // ---- scatter into sorted[] ----
    for (int i = tid; i < CELLS_PER_BIN; i += 512) {
        const int c = i / CAP_CELL;
        const int s = i - c * CAP_CELL;
        if (s < (int)cnt_c[c]) {
            const int key = raw[i].y & (NKEYS - 1);
            const int p = atomicAdd(&cur[key], 1);
            const int dst = starts[key] + p;
            if (dst < CAP) sorted[dst] = raw[i].x;
        }
    }
    __syncthreads();

    // ---- gather: two rows per wave, lane owns 4 features ----
    const int wave = tid >> 6;
    const int lane = tid & 63;
    const int half = lane >> 5;                     // 0: row A, 1: row B
    const int hl   = lane & 31;                     // feature group 0..31
    const float4 b = bias4[hl];

    #pragma unroll
    for (int rp = 0; rp < 4; ++rp) {
        const int row  = wave + 16 * rp + 8 * half;
        const int node = bin * BIN_ROWS + row;
        int s = 0, len = 0;
        if (node < N_NODES) {
            s   = starts[row << 3];                 // row segment spans 8 keys
            len = starts[(row << 3) + 8] - s;
        }
        int lm = len;
        lm = max(lm, __shfl_xor(lm, 32));           // pair-max iteration count

        float4 acc = {0.f, 0.f, 0.f, 0.f};
        for (int j0 = 0; j0 < lm; j0 += 8) {
            uint2 hv[8];
            float vv[8];
            #pragma unroll
            for (int q = 0; q < 8; ++q) {
                const int jq = j0 + q;
                const int jj = (jq < len) ? (s + jq) : 0;
                unsigned ed = sorted[jj];            // LDS broadcast per half
                ed = (jq < len) ? ed : 0u;
                vv[q] = __uint_as_float((ed & 0xffffu) << 16);
                hv[q] = hb2[(size_t)(ed >> 16) * 32 + hl];   // 8B/lane, coalesced
            }
            #pragma unroll
            for (int q = 0; q < 8; ++q) {
                acc.x = fmaf(vv[q], ubf_lo(hv[q].x), acc.x);
                acc.y = fmaf(vv[q], ubf_hi(hv[q].x), acc.y);
                acc.z = fmaf(vv[q], ubf_lo(hv[q].y), acc.z);
                acc.w = fmaf(vv[q], ubf_hi(hv[q].y), acc.w);
            }
        }
        if (node < N_NODES) {
            float4 o;
            o.x = fmaxf(acc.x + b.x, 0.f);
            o.y = fmaxf(acc.y + b.y, 0.f);
            o.z = fmaxf(acc.z + b.z, 0.f);
            o.w = fmaxf(acc.w + b.w, 0.f);
            out4[(size_t)node * 32 + hl] = o;
        }
    }
}

extern "C" void kernel_launch(void* const* d_in, const int* in_sizes, int n_in,
                              void* d_out, int out_size, void* d_ws, size_t ws_size,
                              hipStream_t stream) {
    const float* x      = (const float*)d_in[0];   // [N_NODES, D]
    const float* weight = (const float*)d_in[1];   // [D, D]
    const float* bias   = (const float*)d_in[2];   // [D]
    const float* vals   = (const float*)d_in[3];   // [N_EDGES]
    const int*   rowi   = (const int*)d_in[4];     // [N_EDGES]
    const int*   coli   = (const int*)d_in[5];     // [N_EDGES]
    float* out = (float*)d_out;                    // [N_NODES, D]

    // Workspace layout (16B-aligned):
    //   hb    : N_NODES*128 ushorts (bf16 h)                  = 12.8 MB
    //   wt    : 128*64 uints (bf16 W^T, k-packed)             = 32 KB
    //   cells : NBINS*NCHUNK*CAP_CELL uint2 (cell table)      = 29.4 MB
    //   cnt_t : NCHUNK*CNTROW ushorts (transposed counts)     = 307 KB
    char* w = (char*)d_ws;
    ushort*   hb    = (ushort*)w;   w += (size_t)N_NODES * D * sizeof(ushort);
    unsigned* wt    = (unsigned*)w; w += (size_t)D * 64 * sizeof(unsigned);
    uint2*    cells = (uint2*)w;    w += (size_t)NBINS * CELLS_PER_BIN * sizeof(uint2);
    ushort*   cnt_t = (ushort*)w;

    // 1) build bf16 W^T
    prep_wt<<<32, 256, 0, stream>>>(weight, wt);

    // 2) partition (cell-table, atomic-free, first) || GEMM (MFMA bf16)
    fused_partition_gemm<<<NCHUNK + GEMM_BLOCKS, 256, 0, stream>>>(
        (const float4*)x, (const uint4*)wt, hb,
        (const int4*)rowi, (const int4*)coli, (const float4*)vals,
        cells, cnt_t);

    // 3) per-bin staged 512-key sort + col-ordered gather + fused bias/ReLU
    sort_gather<<<NBINS, 512, 0, stream>>>(cnt_t, cells, (const uint2*)hb,
                                           (const float4*)bias, (float4*)out);
}